// Round 2
// baseline (16196.982 us; speedup 1.0000x reference)
//
#include <hip/hip_runtime.h>
#include <math.h>

// Problem constants
constexpr int B_  = 2;
constexpr int T_  = 2048;
constexpr int H_  = 12;
constexpr int C_  = 768;
constexpr int D_  = 64;
constexpr int FF_ = 3072;
constexpr int L_  = 12;
constexpr int VP_ = 4098;
constexpr int VF_ = 4096;
constexpr int BT_ = B_ * T_;   // 4096

// ---------------------------------------------------------------------------
// Embedding gather
// ---------------------------------------------------------------------------
__global__ __launch_bounds__(256) void embed_kernel(
    const int* __restrict__ tokens, const int* __restrict__ ttype,
    const float* __restrict__ pos_w, const float* __restrict__ feat_w,
    float* __restrict__ x) {
  int row = blockIdx.x;
  int tok = tokens[row];
  const float* src;
  if (ttype[row] == 1) {
    int t = min(max(tok, 0), VF_ - 1);
    src = feat_w + (size_t)t * C_;
  } else {
    int t = min(max(tok, 0), VP_ - 1);
    src = pos_w + (size_t)t * C_;
  }
  float* dst = x + (size_t)row * C_;
  for (int c = threadIdx.x; c < C_; c += 256) dst[c] = src[c];
}

// ---------------------------------------------------------------------------
// LayerNorm over C=768; one block (256 threads) per row.
// ---------------------------------------------------------------------------
__global__ __launch_bounds__(256) void ln_kernel(
    const float* __restrict__ x, const float* __restrict__ w,
    const float* __restrict__ b, float* __restrict__ out) {
  int row = blockIdx.x;
  const float* xr = x + (size_t)row * C_;
  float vv[3];
  float s = 0.f, s2 = 0.f;
#pragma unroll
  for (int i = 0; i < 3; i++) {
    float t = xr[threadIdx.x + i * 256];
    vv[i] = t; s += t; s2 += t * t;
  }
#pragma unroll
  for (int off = 32; off; off >>= 1) {
    s  += __shfl_xor(s,  off, 64);
    s2 += __shfl_xor(s2, off, 64);
  }
  __shared__ float ss[4], ss2[4];
  int wave = threadIdx.x >> 6, lane = threadIdx.x & 63;
  if (lane == 0) { ss[wave] = s; ss2[wave] = s2; }
  __syncthreads();
  s  = ss[0] + ss[1] + ss[2] + ss[3];
  s2 = ss2[0] + ss2[1] + ss2[2] + ss2[3];
  float mean = s * (1.f / C_);
  float var  = s2 * (1.f / C_) - mean * mean;
  float inv  = 1.f / sqrtf(var + 1e-5f);
  float* orow = out + (size_t)row * C_;
#pragma unroll
  for (int i = 0; i < 3; i++) {
    int c = threadIdx.x + i * 256;
    orow[c] = (vv[i] - mean) * inv * w[c] + b[c];
  }
}

// ---------------------------------------------------------------------------
// Generic GEMM: Co[M,N] = epilogue(A[M,K] @ W[N,K]^T)
// Block tile: 128 x BN (BN = 128 or 64), BK = 16, 256 threads.
// EPI: 0 = plain, 1 = exact GELU, 2 = Co = (*skip_p)*resid + (*rs_p)*acc
// ---------------------------------------------------------------------------
template <int BN, int EPI>
__global__ __launch_bounds__(256) void gemm_xwT(
    const float* __restrict__ A, const float* __restrict__ W,
    float* Co, const float* resid,
    const float* __restrict__ skip_p, const float* __restrict__ rs_p,
    int M, int N, int K) {
  constexpr int BK = 16;
  constexpr int MB = 2;          // two 64-row sub-blocks
  constexpr int NB = BN / 64;    // one or two 64-col sub-blocks
  __shared__ float As[BK][132];      // [k][m], padded
  __shared__ float Ws[BK][BN + 4];   // [k][n], padded

  int bm = blockIdx.y * 128, bn = blockIdx.x * BN;
  int tid = threadIdx.x;
  int tn = tid & 15, tm = tid >> 4;
  int lr = tid >> 2;             // 0..63
  int lk = (tid & 3) * 4;        // 0,4,8,12

  float acc[MB][NB][4][4] = {};
  float4 ar[MB], wr[NB];

  // ---- prologue: load tile 0 into regs, publish to LDS ----
#pragma unroll
  for (int u = 0; u < MB; u++)
    ar[u] = *(const float4*)(A + (size_t)(bm + lr + 64 * u) * K + lk);
#pragma unroll
  for (int v = 0; v < NB; v++) {
    int wrow = bn + lr + 64 * v;
    wr[v] = (wrow < N) ? *(const float4*)(W + (size_t)wrow * K + lk)
                       : make_float4(0.f, 0.f, 0.f, 0.f);
  }
#pragma unroll
  for (int u = 0; u < MB; u++) {
    As[lk + 0][lr + 64 * u] = ar[u].x; As[lk + 1][lr + 64 * u] = ar[u].y;
    As[lk + 2][lr + 64 * u] = ar[u].z; As[lk + 3][lr + 64 * u] = ar[u].w;
  }
#pragma unroll
  for (int v = 0; v < NB; v++) {
    Ws[lk + 0][lr + 64 * v] = wr[v].x; Ws[lk + 1][lr + 64 * v] = wr[v].y;
    Ws[lk + 2][lr + 64 * v] = wr[v].z; Ws[lk + 3][lr + 64 * v] = wr[v].w;
  }
  __syncthreads();

  for (int k0 = 0; k0 < K; k0 += BK) {
    bool has_next = (k0 + BK < K);
    // prefetch next tiles into registers (issued before the FMA loop)
    if (has_next) {
      int kn = k0 + BK;
#pragma unroll
      for (int u = 0; u < MB; u++)
        ar[u] = *(const float4*)(A + (size_t)(bm + lr + 64 * u) * K + kn + lk);
#pragma unroll
      for (int v = 0; v < NB; v++) {
        int wrow = bn + lr + 64 * v;
        wr[v] = (wrow < N) ? *(const float4*)(W + (size_t)wrow * K + kn + lk)
                           : make_float4(0.f, 0.f, 0.f, 0.f);
      }
    }
    // compute on current LDS tiles
#pragma unroll
    for (int kk = 0; kk < BK; kk++) {
      float a[MB][4], b[NB][4];
#pragma unroll
      for (int u = 0; u < MB; u++) {
        float4 a4 = *(const float4*)&As[kk][u * 64 + tm * 4];
        a[u][0] = a4.x; a[u][1] = a4.y; a[u][2] = a4.z; a[u][3] = a4.w;
      }
#pragma unroll
      for (int v = 0; v < NB; v++) {
        float4 b4 = *(const float4*)&Ws[kk][v * 64 + tn * 4];
        b[v][0] = b4.x; b[v][1] = b4.y; b[v][2] = b4.z; b[v][3] = b4.w;
      }
#pragma unroll
      for (int u = 0; u < MB; u++)
#pragma unroll
        for (int v = 0; v < NB; v++)
#pragma unroll
          for (int i = 0; i < 4; i++)
#pragma unroll
            for (int j = 0; j < 4; j++)
              acc[u][v][i][j] += a[u][i] * b[v][j];
    }
    if (has_next) {
      __syncthreads();   // all reads of current tiles done
#pragma unroll
      for (int u = 0; u < MB; u++) {
        As[lk + 0][lr + 64 * u] = ar[u].x; As[lk + 1][lr + 64 * u] = ar[u].y;
        As[lk + 2][lr + 64 * u] = ar[u].z; As[lk + 3][lr + 64 * u] = ar[u].w;
      }
#pragma unroll
      for (int v = 0; v < NB; v++) {
        Ws[lk + 0][lr + 64 * v] = wr[v].x; Ws[lk + 1][lr + 64 * v] = wr[v].y;
        Ws[lk + 2][lr + 64 * v] = wr[v].z; Ws[lk + 3][lr + 64 * v] = wr[v].w;
      }
      __syncthreads();   // new tiles visible
    }
  }

  // ---- epilogue ----
  float skip = 0.f, rs = 0.f;
  if constexpr (EPI == 2) { skip = *skip_p; rs = *rs_p; }
  bool full = (bn + BN <= N) && ((N & 3) == 0);
#pragma unroll
  for (int u = 0; u < MB; u++)
#pragma unroll
    for (int i = 0; i < 4; i++) {
      int m = bm + u * 64 + tm * 4 + i;
#pragma unroll
      for (int v = 0; v < NB; v++) {
        int n = bn + v * 64 + tn * 4;
        float c4[4];
#pragma unroll
        for (int j = 0; j < 4; j++) {
          float c = acc[u][v][i][j];
          if constexpr (EPI == 1)
            c = 0.5f * c * (1.f + erff(c * 0.70710678118654752f));
          if constexpr (EPI == 2) {
            if (n + j < N) c = skip * resid[(size_t)m * N + n + j] + rs * c;
          }
          c4[j] = c;
        }
        if (full) {
          *(float4*)(Co + (size_t)m * N + n) =
              make_float4(c4[0], c4[1], c4[2], c4[3]);
        } else {
#pragma unroll
          for (int j = 0; j < 4; j++)
            if (n + j < N) Co[(size_t)m * N + n + j] = c4[j];
        }
      }
    }
}

// ---------------------------------------------------------------------------
// QKNorm + RoPE3D, in-place on qkv (BT, 3C).
// ---------------------------------------------------------------------------
__global__ __launch_bounds__(256) void qknorm_rope_kernel(
    float* __restrict__ qkv, const int* __restrict__ coords,
    const float* __restrict__ qscale, const float* __restrict__ kscale) {
  int row = blockIdx.x;
  int wave = threadIdx.x >> 6, lane = threadIdx.x & 63;
  int c0 = coords[row * 3 + 0];
  int c1 = coords[row * 3 + 1];
  int c2 = coords[row * 3 + 2];
  for (int g = wave; g < 2 * H_; g += 4) {
    int h = g >> 1, isk = g & 1;
    size_t idx = (size_t)row * (3 * C_) + (size_t)isk * C_ + h * D_ + lane;
    float v = qkv[idx];
    float ssum = v * v;
#pragma unroll
    for (int off = 32; off; off >>= 1) ssum += __shfl_xor(ssum, off, 64);
    float n = sqrtf(ssum * (1.f / D_) + 1e-6f);
    const float* sc = isk ? kscale : qscale;
    float xn = v / n * sc[lane];
    float partner = __shfl_xor(xn, 1, 64);
    float outv = xn;
    if (lane < 60) {
      int p = lane >> 1;
      int axis = p / 10;
      int f = p - axis * 10;
      int crd = (axis == 0) ? c0 : ((axis == 1) ? c1 : c2);
      float invf = expf(-(float)f * 0.1f * 9.210340371976184f);
      float ang = (float)crd * invf;
      float sn, cs;
      sincosf(ang, &sn, &cs);
      if (lane & 1) {
        outv = partner * sn + xn * cs;
      } else {
        outv = xn * cs - partner * sn;
      }
    }
    qkv[idx] = outv;
  }
}

// ---------------------------------------------------------------------------
// Causal flash attention, 64-query tiles.
// Round-1 rework:
//  - stride 76 (was 72) + dim-interleaved transposed staging for Q/K
//    (2-way write aliasing, free) instead of 4/16-way conflicts
//  - XOR swizzle (col ^ ((row&7)<<2)) on V and P tiles: staging writes and
//    PV-phase reads drop from 16-way/4-way to 2-way
//  - register prefetch of next K/V tile issued before the S-loop: global
//    latency hides under ~4k cycles of FMA instead of sitting between barriers
//  - 2 barriers/tile: Ks(t+1) written after P-publish barrier (Ks dead after
//    S), Vs(t+1) written after the post-PV barrier
// ---------------------------------------------------------------------------
constexpr int SK_ = 76;   // LDS row stride (floats)

__global__ __launch_bounds__(256) void attn_kernel(
    const float* __restrict__ qkv, float* __restrict__ out) {
  int bh = blockIdx.y;
  int b = bh / H_, h = bh % H_;
  int q0 = blockIdx.x * 64;
  int tid = threadIdx.x;
  int tn = tid & 15, tm = tid >> 4;
  int lr = tid >> 2;            // row 0..63
  int q4 = (tid & 3) * 4;       // dim base {0,4,8,12}; thread covers q4+16u

  __shared__ float Qs[64 * SK_];  // [d][m] transposed, pre-scaled
  __shared__ float Ks[64 * SK_];  // [d][n] transposed
  __shared__ float Vs[64 * SK_];  // [k][d] row-major, XOR-swizzled cols
  __shared__ float Ps[64 * SK_];  // [m][n] row-major, XOR-swizzled cols

  // ---- prologue: stage Q (scaled) + K/V tile 0 ----
  {
    const float* qsrc = qkv + (size_t)(b * T_ + q0 + lr) * (3 * C_) + h * D_ + q4;
    const float sc = 0.125f;      // 1/sqrt(64)
#pragma unroll
    for (int u = 0; u < 4; u++) {
      float4 v = *(const float4*)(qsrc + u * 16);
      int d = q4 + u * 16;
      Qs[(d + 0) * SK_ + lr] = v.x * sc;
      Qs[(d + 1) * SK_ + lr] = v.y * sc;
      Qs[(d + 2) * SK_ + lr] = v.z * sc;
      Qs[(d + 3) * SK_ + lr] = v.w * sc;
    }
  }
  float4 kreg[4], vreg[4];
  {
    const float* kb = qkv + (size_t)(b * T_ + lr) * (3 * C_) + C_ + h * D_ + q4;
#pragma unroll
    for (int u = 0; u < 4; u++) kreg[u] = *(const float4*)(kb + u * 16);
    const float* vb = kb + C_;
#pragma unroll
    for (int u = 0; u < 4; u++) vreg[u] = *(const float4*)(vb + u * 16);
  }
#pragma unroll
  for (int u = 0; u < 4; u++) {
    int d = q4 + u * 16;
    Ks[(d + 0) * SK_ + lr] = kreg[u].x;
    Ks[(d + 1) * SK_ + lr] = kreg[u].y;
    Ks[(d + 2) * SK_ + lr] = kreg[u].z;
    Ks[(d + 3) * SK_ + lr] = kreg[u].w;
  }
#pragma unroll
  for (int u = 0; u < 4; u++)
    *(float4*)&Vs[lr * SK_ + ((q4 + u * 16) ^ ((lr & 7) << 2))] = vreg[u];
  __syncthreads();

  float accO[4][4] = {};
  float mrow[4], lrow[4];
#pragma unroll
  for (int i = 0; i < 4; i++) { mrow[i] = -1e30f; lrow[i] = 0.f; }

  for (int k0 = 0; k0 <= q0; k0 += 64) {
    bool more = (k0 + 64 <= q0);
    // prefetch next K/V tile into registers; latency hides under S + softmax
    if (more) {
      const float* kb =
          qkv + (size_t)(b * T_ + k0 + 64 + lr) * (3 * C_) + C_ + h * D_ + q4;
#pragma unroll
      for (int u = 0; u < 4; u++) kreg[u] = *(const float4*)(kb + u * 16);
      const float* vb = kb + C_;
#pragma unroll
      for (int u = 0; u < 4; u++) vreg[u] = *(const float4*)(vb + u * 16);
    }

    // S tile: s[i][j] = Q[q0+tm*4+i] . K[k0+tn*4+j]  (Q pre-scaled)
    float s[4][4] = {};
#pragma unroll
    for (int d = 0; d < 64; d++) {
      float4 a4 = *(const float4*)&Qs[d * SK_ + tm * 4];
      float4 b4 = *(const float4*)&Ks[d * SK_ + tn * 4];
      float a[4] = {a4.x, a4.y, a4.z, a4.w};
      float bb[4] = {b4.x, b4.y, b4.z, b4.w};
#pragma unroll
      for (int i = 0; i < 4; i++)
#pragma unroll
        for (int j = 0; j < 4; j++) s[i][j] += a[i] * bb[j];
    }

    // Causal mask: only the diagonal tile can have invalid entries
    if (k0 == q0) {
#pragma unroll
      for (int i = 0; i < 4; i++)
#pragma unroll
        for (int j = 0; j < 4; j++)
          if (tn * 4 + j > tm * 4 + i) s[i][j] = -1e30f;
    }

    // Online softmax per row (16-lane shfl groups share a row)
#pragma unroll
    for (int i = 0; i < 4; i++) {
      float rm = fmaxf(fmaxf(s[i][0], s[i][1]), fmaxf(s[i][2], s[i][3]));
#pragma unroll
      for (int off = 1; off < 16; off <<= 1) rm = fmaxf(rm, __shfl_xor(rm, off, 64));
      float mnew = fmaxf(mrow[i], rm);
      float alpha = __expf(mrow[i] - mnew);
      mrow[i] = mnew;
      float rs = 0.f;
#pragma unroll
      for (int j = 0; j < 4; j++) {
        float p = __expf(s[i][j] - mnew);
        s[i][j] = p;
        rs += p;
      }
#pragma unroll
      for (int off = 1; off < 16; off <<= 1) rs += __shfl_xor(rs, off, 64);
      lrow[i] = lrow[i] * alpha + rs;
#pragma unroll
      for (int j = 0; j < 4; j++) accO[i][j] *= alpha;
    }

    // Publish P tile (swizzled)
#pragma unroll
    for (int i = 0; i < 4; i++) {
      int r = tm * 4 + i;
      *(float4*)&Ps[r * SK_ + ((tn * 4) ^ ((r & 7) << 2))] =
          make_float4(s[i][0], s[i][1], s[i][2], s[i][3]);
    }
    __syncthreads();   // Ps visible; all S-reads of Ks done

    // Ks is dead now — stage next K tile while PV runs
    if (more) {
#pragma unroll
      for (int u = 0; u < 4; u++) {
        int d = q4 + u * 16;
        Ks[(d + 0) * SK_ + lr] = kreg[u].x;
        Ks[(d + 1) * SK_ + lr] = kreg[u].y;
        Ks[(d + 2) * SK_ + lr] = kreg[u].z;
        Ks[(d + 3) * SK_ + lr] = kreg[u].w;
      }
    }

    // O += P @ V  (64x64x64 register-tiled, swizzled reads)
#pragma unroll
    for (int kk = 0; kk < 64; kk += 4) {
      float pi[4][4], vu[4][4];
#pragma unroll
      for (int i = 0; i < 4; i++) {
        int r = tm * 4 + i;
        float4 p4 = *(const float4*)&Ps[r * SK_ + (kk ^ ((r & 7) << 2))];
        pi[i][0] = p4.x; pi[i][1] = p4.y; pi[i][2] = p4.z; pi[i][3] = p4.w;
      }
#pragma unroll
      for (int u = 0; u < 4; u++) {
        int k = kk + u;
        float4 v4 = *(const float4*)&Vs[k * SK_ + ((tn * 4) ^ ((k & 7) << 2))];
        vu[u][0] = v4.x; vu[u][1] = v4.y; vu[u][2] = v4.z; vu[u][3] = v4.w;
      }
#pragma unroll
      for (int u = 0; u < 4; u++)
#pragma unroll
        for (int i = 0; i < 4; i++)
#pragma unroll
          for (int j = 0; j < 4; j++) accO[i][j] += pi[i][u] * vu[u][j];
    }
    __syncthreads();   // PV reads of Vs/Ps done; Ks(t+1) visible

    // Vs is dead now — stage next V tile (visible at next tile's first barrier)
    if (more) {
#pragma unroll
      for (int u = 0; u < 4; u++)
        *(float4*)&Vs[lr * SK_ + ((q4 + u * 16) ^ ((lr & 7) << 2))] = vreg[u];
    }
  }

  // Write out: rows q0+tm*4+i, dims tn*4+j of head h
#pragma unroll
  for (int i = 0; i < 4; i++) {
    float inv = 1.f / lrow[i];
    float4 o = make_float4(accO[i][0] * inv, accO[i][1] * inv,
                           accO[i][2] * inv, accO[i][3] * inv);
    *(float4*)(out + (size_t)(b * T_ + q0 + tm * 4 + i) * C_ + h * D_ + tn * 4) = o;
  }
}

// ---------------------------------------------------------------------------
// Orchestration
// ---------------------------------------------------------------------------
extern "C" void kernel_launch(void* const* d_in, const int* in_sizes, int n_in,
                              void* d_out, int out_size, void* d_ws, size_t ws_size,
                              hipStream_t stream) {
  const int*   tokens    = (const int*)d_in[0];
  const int*   coords    = (const int*)d_in[1];
  const int*   ttype     = (const int*)d_in[2];
  const float* pos_emb   = (const float*)d_in[3];
  const float* feat_emb  = (const float*)d_in[4];
  const float* qkv_w     = (const float*)d_in[5];
  const float* out_w     = (const float*)d_in[6];
  const float* q_scale   = (const float*)d_in[7];
  const float* k_scale   = (const float*)d_in[8];
  const float* ln1_w     = (const float*)d_in[9];
  const float* ln1_b     = (const float*)d_in[10];
  const float* ln2_w     = (const float*)d_in[11];
  const float* ln2_b     = (const float*)d_in[12];
  const float* fc1_w     = (const float*)d_in[13];
  const float* fc2_w     = (const float*)d_in[14];
  const float* res_a     = (const float*)d_in[15];
  const float* res_m     = (const float*)d_in[16];
  const float* skip_a    = (const float*)d_in[17];
  const float* skip_m    = (const float*)d_in[18];
  const float* lnf_w     = (const float*)d_in[19];
  const float* lnf_b     = (const float*)d_in[20];
  const float* pos_head  = (const float*)d_in[21];
  const float* feat_head = (const float*)d_in[22];
  float* out = (float*)d_out;

  float* ws    = (float*)d_ws;
  float* x     = ws;                                   // BT*C
  float* hbuf  = x     + (size_t)BT_ * C_;             // BT*C
  float* qkvb  = hbuf  + (size_t)BT_ * C_;             // BT*3C
  float* attnb = qkvb  + (size_t)BT_ * 3 * C_;         // BT*C
  float* ffb   = attnb + (size_t)BT_ * C_;             // BT*FF

  embed_kernel<<<BT_, 256, 0, stream>>>(tokens, ttype, pos_emb, feat_emb, x);

  for (int l = 0; l < L_; l++) {
    ln_kernel<<<BT_, 256, 0, stream>>>(x, ln1_w + l * C_, ln1_b + l * C_, hbuf);
    gemm_xwT<128, 0><<<dim3((3 * C_) / 128, BT_ / 128), 256, 0, stream>>>(
        hbuf, qkv_w + (size_t)l * 3 * C_ * C_, qkvb, nullptr, nullptr, nullptr,
        BT_, 3 * C_, C_);
    qknorm_rope_kernel<<<BT_, 256, 0, stream>>>(qkvb, coords,
                                                q_scale + l * D_, k_scale + l * D_);
    attn_kernel<<<dim3(T_ / 64, B_ * H_), 256, 0, stream>>>(qkvb, attnb);
    gemm_xwT<64, 2><<<dim3(C_ / 64, BT_ / 128), 256, 0, stream>>>(
        attnb, out_w + (size_t)l * C_ * C_, x, x, skip_a + l, res_a + l,
        BT_, C_, C_);
    ln_kernel<<<BT_, 256, 0, stream>>>(x, ln2_w + l * C_, ln2_b + l * C_, hbuf);
    gemm_xwT<128, 1><<<dim3(FF_ / 128, BT_ / 128), 256, 0, stream>>>(
        hbuf, fc1_w + (size_t)l * FF_ * C_, ffb, nullptr, nullptr, nullptr,
        BT_, FF_, C_);
    gemm_xwT<64, 2><<<dim3(C_ / 64, BT_ / 128), 256, 0, stream>>>(
        ffb, fc2_w + (size_t)l * C_ * FF_, x, x, skip_m + l, res_m + l,
        BT_, C_, FF_);
  }

  ln_kernel<<<BT_, 256, 0, stream>>>(x, lnf_w, lnf_b, hbuf);
  gemm_xwT<128, 0><<<dim3((VP_ + 127) / 128, BT_ / 128), 256, 0, stream>>>(
      hbuf, pos_head, out, nullptr, nullptr, nullptr, BT_, VP_, C_);
  gemm_xwT<128, 0><<<dim3(VF_ / 128, BT_ / 128), 256, 0, stream>>>(
      hbuf, feat_head, out + (size_t)BT_ * VP_, nullptr, nullptr, nullptr,
      BT_, VF_, C_);
}

// Round 3
// 13012.894 us; speedup vs baseline: 1.2447x; 1.2447x over previous
//
#include <hip/hip_runtime.h>
#include <math.h>

// Problem constants
constexpr int B_  = 2;
constexpr int T_  = 2048;
constexpr int H_  = 12;
constexpr int C_  = 768;
constexpr int D_  = 64;
constexpr int FF_ = 3072;
constexpr int L_  = 12;
constexpr int VP_ = 4098;
constexpr int VF_ = 4096;
constexpr int BT_ = B_ * T_;   // 4096

typedef __attribute__((ext_vector_type(8))) short bf16x8;
typedef __attribute__((ext_vector_type(4))) float f32x4;

// ---------------------------------------------------------------------------
// Embedding gather
// ---------------------------------------------------------------------------
__global__ __launch_bounds__(256) void embed_kernel(
    const int* __restrict__ tokens, const int* __restrict__ ttype,
    const float* __restrict__ pos_w, const float* __restrict__ feat_w,
    float* __restrict__ x) {
  int row = blockIdx.x;
  int tok = tokens[row];
  const float* src;
  if (ttype[row] == 1) {
    int t = min(max(tok, 0), VF_ - 1);
    src = feat_w + (size_t)t * C_;
  } else {
    int t = min(max(tok, 0), VP_ - 1);
    src = pos_w + (size_t)t * C_;
  }
  float* dst = x + (size_t)row * C_;
  for (int c = threadIdx.x; c < C_; c += 256) dst[c] = src[c];
}

// ---------------------------------------------------------------------------
// LayerNorm over C=768; one block (256 threads) per row.
// ---------------------------------------------------------------------------
__global__ __launch_bounds__(256) void ln_kernel(
    const float* __restrict__ x, const float* __restrict__ w,
    const float* __restrict__ b, float* __restrict__ out) {
  int row = blockIdx.x;
  const float* xr = x + (size_t)row * C_;
  float vv[3];
  float s = 0.f, s2 = 0.f;
#pragma unroll
  for (int i = 0; i < 3; i++) {
    float t = xr[threadIdx.x + i * 256];
    vv[i] = t; s += t; s2 += t * t;
  }
#pragma unroll
  for (int off = 32; off; off >>= 1) {
    s  += __shfl_xor(s,  off, 64);
    s2 += __shfl_xor(s2, off, 64);
  }
  __shared__ float ss[4], ss2[4];
  int wave = threadIdx.x >> 6, lane = threadIdx.x & 63;
  if (lane == 0) { ss[wave] = s; ss2[wave] = s2; }
  __syncthreads();
  s  = ss[0] + ss[1] + ss[2] + ss[3];
  s2 = ss2[0] + ss2[1] + ss2[2] + ss2[3];
  float mean = s * (1.f / C_);
  float var  = s2 * (1.f / C_) - mean * mean;
  float inv  = 1.f / sqrtf(var + 1e-5f);
  float* orow = out + (size_t)row * C_;
#pragma unroll
  for (int i = 0; i < 3; i++) {
    int c = threadIdx.x + i * 256;
    orow[c] = (vv[i] - mean) * inv * w[c] + b[c];
  }
}

// ---------------------------------------------------------------------------
// Split-bf16 MFMA GEMM: Co[M,N] = epilogue(A[M,K] @ W[N,K]^T)
// A = Ah + Al, W = Wh + Wl (bf16 truncation split);
// A@W^T ~= Ah Wh + Ah Wl + Al Wh  (fp32 MFMA accumulate; lo*lo dropped ~2^-16)
// Block: 128x128 tile, BK=32, 256 threads = 4 waves (2x2), wave tile 64x64
// = 4x4 fragments of v_mfma_f32_16x16x32_bf16.
// LDS rows padded to 40 bf16 (20-word stride -> conflict-free b128 frag reads).
// EPI: 0 = plain, 1 = exact GELU, 2 = Co = (*skip_p)*resid + (*rs_p)*acc
// ---------------------------------------------------------------------------
__device__ inline void cvt4(float4 v, unsigned int hi[2], unsigned int lo[2]) {
  unsigned int b0 = __float_as_uint(v.x), b1 = __float_as_uint(v.y);
  unsigned int b2 = __float_as_uint(v.z), b3 = __float_as_uint(v.w);
  hi[0] = (b0 >> 16) | (b1 & 0xFFFF0000u);
  hi[1] = (b2 >> 16) | (b3 & 0xFFFF0000u);
  float h0 = __uint_as_float(b0 & 0xFFFF0000u);
  float h1 = __uint_as_float(b1 & 0xFFFF0000u);
  float h2 = __uint_as_float(b2 & 0xFFFF0000u);
  float h3 = __uint_as_float(b3 & 0xFFFF0000u);
  unsigned int l0 = __float_as_uint(v.x - h0);
  unsigned int l1 = __float_as_uint(v.y - h1);
  unsigned int l2 = __float_as_uint(v.z - h2);
  unsigned int l3 = __float_as_uint(v.w - h3);
  lo[0] = (l0 >> 16) | (l1 & 0xFFFF0000u);
  lo[1] = (l2 >> 16) | (l3 & 0xFFFF0000u);
}

template <int EPI>
__global__ __launch_bounds__(256) void gemm_mfma(
    const float* __restrict__ A, const float* __restrict__ W,
    float* Co, const float* resid,
    const float* __restrict__ skip_p, const float* __restrict__ rs_p,
    int M, int N, int K) {
  constexpr int SR = 40;   // LDS row stride in bf16 (32 data + 8 pad)
  __shared__ unsigned short AsH[128 * SR];
  __shared__ unsigned short AsL[128 * SR];
  __shared__ unsigned short WsH[128 * SR];
  __shared__ unsigned short WsL[128 * SR];

  int bm = blockIdx.y * 128, bn = blockIdx.x * 128;
  int tid = threadIdx.x;
  int lane = tid & 63, wv = tid >> 6;
  int wm = (wv >> 1) * 64, wn = (wv & 1) * 64;
  int fr = lane & 15;          // fragment row/col within 16
  int ko = (lane >> 4) * 8;    // k-offset (8 bf16 per lane)

  // staging map: 2 threads per row, each 4 float4 (16 floats) of the 32-K row
  int srow = tid >> 1;
  int skq  = (tid & 1) * 4;    // float4 index base within row

  f32x4 acc[4][4] = {};
  float4 apf[4], wpf[4];

  const float* Arow = A + (size_t)(bm + srow) * K + skq * 4;
  const float* Wrow = W + (size_t)(bn + srow) * K + skq * 4;
  bool wvalid = (bn + srow) < N;

  // ---- prologue: tile 0 ----
#pragma unroll
  for (int u = 0; u < 4; u++) {
    apf[u] = *(const float4*)(Arow + u * 4);
    wpf[u] = wvalid ? *(const float4*)(Wrow + u * 4)
                    : make_float4(0.f, 0.f, 0.f, 0.f);
  }
  {
    unsigned int h[2], l[2];
#pragma unroll
    for (int u = 0; u < 4; u++) {
      int off = srow * SR + (skq + u) * 4;
      cvt4(apf[u], h, l);
      *(uint2*)&AsH[off] = make_uint2(h[0], h[1]);
      *(uint2*)&AsL[off] = make_uint2(l[0], l[1]);
      cvt4(wpf[u], h, l);
      *(uint2*)&WsH[off] = make_uint2(h[0], h[1]);
      *(uint2*)&WsL[off] = make_uint2(l[0], l[1]);
    }
  }
  __syncthreads();

  const unsigned short* aHp = &AsH[(wm + fr) * SR + ko];
  const unsigned short* aLp = &AsL[(wm + fr) * SR + ko];
  const unsigned short* bHp = &WsH[(wn + fr) * SR + ko];
  const unsigned short* bLp = &WsL[(wn + fr) * SR + ko];

  for (int k0 = 0; k0 < K; k0 += 32) {
    bool has_next = (k0 + 32 < K);
    if (has_next) {
#pragma unroll
      for (int u = 0; u < 4; u++) {
        apf[u] = *(const float4*)(Arow + k0 + 32 + u * 4);
        wpf[u] = wvalid ? *(const float4*)(Wrow + k0 + 32 + u * 4)
                        : make_float4(0.f, 0.f, 0.f, 0.f);
      }
    }

    // compute on current LDS tile
    bf16x8 aH[4], aL[4];
#pragma unroll
    for (int fm = 0; fm < 4; fm++) {
      aH[fm] = *(const bf16x8*)(aHp + fm * 16 * SR);
      aL[fm] = *(const bf16x8*)(aLp + fm * 16 * SR);
    }
#pragma unroll
    for (int fn = 0; fn < 4; fn++) {
      bf16x8 bH = *(const bf16x8*)(bHp + fn * 16 * SR);
      bf16x8 bL = *(const bf16x8*)(bLp + fn * 16 * SR);
#pragma unroll
      for (int fm = 0; fm < 4; fm++) {
        acc[fm][fn] = __builtin_amdgcn_mfma_f32_16x16x32_bf16(
            aH[fm], bH, acc[fm][fn], 0, 0, 0);
        acc[fm][fn] = __builtin_amdgcn_mfma_f32_16x16x32_bf16(
            aH[fm], bL, acc[fm][fn], 0, 0, 0);
        acc[fm][fn] = __builtin_amdgcn_mfma_f32_16x16x32_bf16(
            aL[fm], bH, acc[fm][fn], 0, 0, 0);
      }
    }

    if (has_next) {
      __syncthreads();
      unsigned int h[2], l[2];
#pragma unroll
      for (int u = 0; u < 4; u++) {
        int off = srow * SR + (skq + u) * 4;
        cvt4(apf[u], h, l);
        *(uint2*)&AsH[off] = make_uint2(h[0], h[1]);
        *(uint2*)&AsL[off] = make_uint2(l[0], l[1]);
        cvt4(wpf[u], h, l);
        *(uint2*)&WsH[off] = make_uint2(h[0], h[1]);
        *(uint2*)&WsL[off] = make_uint2(l[0], l[1]);
      }
      __syncthreads();
    }
  }

  // ---- epilogue ----
  float skip = 0.f, rs = 0.f;
  if constexpr (EPI == 2) { skip = *skip_p; rs = *rs_p; }
#pragma unroll
  for (int fn = 0; fn < 4; fn++) {
    int col = bn + wn + fn * 16 + fr;
    if (col >= N) continue;
#pragma unroll
    for (int fm = 0; fm < 4; fm++) {
      f32x4 c = acc[fm][fn];
#pragma unroll
      for (int j = 0; j < 4; j++) {
        int row = bm + wm + fm * 16 + (lane >> 4) * 4 + j;
        float cv = c[j];
        if constexpr (EPI == 1)
          cv = 0.5f * cv * (1.f + erff(cv * 0.70710678118654752f));
        if constexpr (EPI == 2)
          cv = skip * resid[(size_t)row * N + col] + rs * cv;
        Co[(size_t)row * N + col] = cv;
      }
    }
  }
}

// ---------------------------------------------------------------------------
// QKNorm + RoPE3D, in-place on qkv (BT, 3C).
// ---------------------------------------------------------------------------
__global__ __launch_bounds__(256) void qknorm_rope_kernel(
    float* __restrict__ qkv, const int* __restrict__ coords,
    const float* __restrict__ qscale, const float* __restrict__ kscale) {
  int row = blockIdx.x;
  int wave = threadIdx.x >> 6, lane = threadIdx.x & 63;
  int c0 = coords[row * 3 + 0];
  int c1 = coords[row * 3 + 1];
  int c2 = coords[row * 3 + 2];
  for (int g = wave; g < 2 * H_; g += 4) {
    int h = g >> 1, isk = g & 1;
    size_t idx = (size_t)row * (3 * C_) + (size_t)isk * C_ + h * D_ + lane;
    float v = qkv[idx];
    float ssum = v * v;
#pragma unroll
    for (int off = 32; off; off >>= 1) ssum += __shfl_xor(ssum, off, 64);
    float n = sqrtf(ssum * (1.f / D_) + 1e-6f);
    const float* sc = isk ? kscale : qscale;
    float xn = v / n * sc[lane];
    float partner = __shfl_xor(xn, 1, 64);
    float outv = xn;
    if (lane < 60) {
      int p = lane >> 1;
      int axis = p / 10;
      int f = p - axis * 10;
      int crd = (axis == 0) ? c0 : ((axis == 1) ? c1 : c2);
      float invf = expf(-(float)f * 0.1f * 9.210340371976184f);
      float ang = (float)crd * invf;
      float sn, cs;
      sincosf(ang, &sn, &cs);
      if (lane & 1) {
        outv = partner * sn + xn * cs;
      } else {
        outv = xn * cs - partner * sn;
      }
    }
    qkv[idx] = outv;
  }
}

// ---------------------------------------------------------------------------
// Causal flash attention, 64-query tiles (R0-exact known-good version).
// ---------------------------------------------------------------------------
__global__ __launch_bounds__(256) void attn_kernel(
    const float* __restrict__ qkv, float* __restrict__ out) {
  int bh = blockIdx.y;
  int b = bh / H_, h = bh % H_;
  int q0 = blockIdx.x * 64;
  int tid = threadIdx.x;
  int tn = tid & 15, tm = tid >> 4;

  __shared__ float Qs[64][72];  // [d][m], pre-scaled by 1/sqrt(D)
  __shared__ float Ks[64][72];  // [d][n]
  __shared__ float Vs[64][72];  // [k][d]
  __shared__ float Ps[64][72];  // [m][n]

  // Stage Q transposed, scaled
  {
    int lr = tid >> 2;            // query row 0..63
    int ld = (tid & 3) * 16;      // dim offset
    const float* src = qkv + (size_t)(b * T_ + q0 + lr) * (3 * C_) + h * D_ + ld;
    const float sc = 0.125f;      // 1/sqrt(64)
#pragma unroll
    for (int u = 0; u < 4; u++) {
      float4 v = ((const float4*)src)[u];
      Qs[ld + u * 4 + 0][lr] = v.x * sc;
      Qs[ld + u * 4 + 1][lr] = v.y * sc;
      Qs[ld + u * 4 + 2][lr] = v.z * sc;
      Qs[ld + u * 4 + 3][lr] = v.w * sc;
    }
  }

  float accO[4][4] = {};
  float mrow[4], lrow[4];
#pragma unroll
  for (int i = 0; i < 4; i++) { mrow[i] = -1e30f; lrow[i] = 0.f; }

  for (int k0 = 0; k0 <= q0; k0 += 64) {
    __syncthreads();  // prev-iter Ps/Vs reads done; Qs published on iter 0
    // Stage K transposed + V natural
    {
      int lr = tid >> 2;          // key row 0..63
      int ld = (tid & 3) * 16;
      const float* kb = qkv + (size_t)(b * T_ + k0 + lr) * (3 * C_) + C_ + h * D_ + ld;
#pragma unroll
      for (int u = 0; u < 4; u++) {
        float4 v = ((const float4*)kb)[u];
        Ks[ld + u * 4 + 0][lr] = v.x;
        Ks[ld + u * 4 + 1][lr] = v.y;
        Ks[ld + u * 4 + 2][lr] = v.z;
        Ks[ld + u * 4 + 3][lr] = v.w;
      }
      const float* vb = kb + C_;
#pragma unroll
      for (int u = 0; u < 4; u++) {
        *(float4*)&Vs[lr][ld + u * 4] = ((const float4*)vb)[u];
      }
    }
    __syncthreads();

    // S tile: s[i][j] = Q[q0+tm*4+i] . K[k0+tn*4+j]  (Q pre-scaled)
    float s[4][4] = {};
#pragma unroll
    for (int d = 0; d < 64; d++) {
      float4 a4 = *(const float4*)&Qs[d][tm * 4];
      float4 b4 = *(const float4*)&Ks[d][tn * 4];
      float a[4] = {a4.x, a4.y, a4.z, a4.w};
      float bb[4] = {b4.x, b4.y, b4.z, b4.w};
#pragma unroll
      for (int i = 0; i < 4; i++)
#pragma unroll
        for (int j = 0; j < 4; j++) s[i][j] += a[i] * bb[j];
    }

    // Causal mask: only the diagonal tile can have invalid entries
    if (k0 == q0) {
#pragma unroll
      for (int i = 0; i < 4; i++)
#pragma unroll
        for (int j = 0; j < 4; j++)
          if (tn * 4 + j > tm * 4 + i) s[i][j] = -1e30f;
    }

    // Online softmax per row (16-lane shfl groups share a row)
#pragma unroll
    for (int i = 0; i < 4; i++) {
      float rm = fmaxf(fmaxf(s[i][0], s[i][1]), fmaxf(s[i][2], s[i][3]));
#pragma unroll
      for (int off = 1; off < 16; off <<= 1) rm = fmaxf(rm, __shfl_xor(rm, off, 64));
      float mnew = fmaxf(mrow[i], rm);
      float alpha = __expf(mrow[i] - mnew);
      mrow[i] = mnew;
      float rs = 0.f;
#pragma unroll
      for (int j = 0; j < 4; j++) {
        float p = __expf(s[i][j] - mnew);
        s[i][j] = p;
        rs += p;
      }
#pragma unroll
      for (int off = 1; off < 16; off <<= 1) rs += __shfl_xor(rs, off, 64);
      lrow[i] = lrow[i] * alpha + rs;
#pragma unroll
      for (int j = 0; j < 4; j++) accO[i][j] *= alpha;
    }

    // Publish P tile
#pragma unroll
    for (int i = 0; i < 4; i++)
      *(float4*)&Ps[tm * 4 + i][tn * 4] = make_float4(s[i][0], s[i][1], s[i][2], s[i][3]);
    __syncthreads();

    // O += P @ V  (64x64x64 register-tiled)
#pragma unroll
    for (int kk = 0; kk < 64; kk += 4) {
      float pi[4][4], vu[4][4];
#pragma unroll
      for (int i = 0; i < 4; i++) {
        float4 p4 = *(const float4*)&Ps[tm * 4 + i][kk];
        pi[i][0] = p4.x; pi[i][1] = p4.y; pi[i][2] = p4.z; pi[i][3] = p4.w;
      }
#pragma unroll
      for (int u = 0; u < 4; u++) {
        float4 v4 = *(const float4*)&Vs[kk + u][tn * 4];
        vu[u][0] = v4.x; vu[u][1] = v4.y; vu[u][2] = v4.z; vu[u][3] = v4.w;
      }
#pragma unroll
      for (int u = 0; u < 4; u++)
#pragma unroll
        for (int i = 0; i < 4; i++)
#pragma unroll
          for (int j = 0; j < 4; j++) accO[i][j] += pi[i][u] * vu[u][j];
    }
  }

  // Write out: rows q0+tm*4+i, dims tn*4+j of head h
#pragma unroll
  for (int i = 0; i < 4; i++) {
    float inv = 1.f / lrow[i];
    float4 o = make_float4(accO[i][0] * inv, accO[i][1] * inv,
                           accO[i][2] * inv, accO[i][3] * inv);
    *(float4*)(out + (size_t)(b * T_ + q0 + tm * 4 + i) * C_ + h * D_ + tn * 4) = o;
  }
}

// ---------------------------------------------------------------------------
// Orchestration
// ---------------------------------------------------------------------------
extern "C" void kernel_launch(void* const* d_in, const int* in_sizes, int n_in,
                              void* d_out, int out_size, void* d_ws, size_t ws_size,
                              hipStream_t stream) {
  const int*   tokens    = (const int*)d_in[0];
  const int*   coords    = (const int*)d_in[1];
  const int*   ttype     = (const int*)d_in[2];
  const float* pos_emb   = (const float*)d_in[3];
  const float* feat_emb  = (const float*)d_in[4];
  const float* qkv_w     = (const float*)d_in[5];
  const float* out_w     = (const float*)d_in[6];
  const float* q_scale   = (const float*)d_in[7];
  const float* k_scale   = (const float*)d_in[8];
  const float* ln1_w     = (const float*)d_in[9];
  const float* ln1_b     = (const float*)d_in[10];
  const float* ln2_w     = (const float*)d_in[11];
  const float* ln2_b     = (const float*)d_in[12];
  const float* fc1_w     = (const float*)d_in[13];
  const float* fc2_w     = (const float*)d_in[14];
  const float* res_a     = (const float*)d_in[15];
  const float* res_m     = (const float*)d_in[16];
  const float* skip_a    = (const float*)d_in[17];
  const float* skip_m    = (const float*)d_in[18];
  const float* lnf_w     = (const float*)d_in[19];
  const float* lnf_b     = (const float*)d_in[20];
  const float* pos_head  = (const float*)d_in[21];
  const float* feat_head = (const float*)d_in[22];
  float* out = (float*)d_out;

  float* ws    = (float*)d_ws;
  float* x     = ws;                                   // BT*C
  float* hbuf  = x     + (size_t)BT_ * C_;             // BT*C
  float* qkvb  = hbuf  + (size_t)BT_ * C_;             // BT*3C
  float* attnb = qkvb  + (size_t)BT_ * 3 * C_;         // BT*C
  float* ffb   = attnb + (size_t)BT_ * C_;             // BT*FF

  embed_kernel<<<BT_, 256, 0, stream>>>(tokens, ttype, pos_emb, feat_emb, x);

  for (int l = 0; l < L_; l++) {
    ln_kernel<<<BT_, 256, 0, stream>>>(x, ln1_w + l * C_, ln1_b + l * C_, hbuf);
    gemm_mfma<0><<<dim3((3 * C_) / 128, BT_ / 128), 256, 0, stream>>>(
        hbuf, qkv_w + (size_t)l * 3 * C_ * C_, qkvb, nullptr, nullptr, nullptr,
        BT_, 3 * C_, C_);
    qknorm_rope_kernel<<<BT_, 256, 0, stream>>>(qkvb, coords,
                                                q_scale + l * D_, k_scale + l * D_);
    attn_kernel<<<dim3(T_ / 64, B_ * H_), 256, 0, stream>>>(qkvb, attnb);
    gemm_mfma<2><<<dim3(C_ / 128, BT_ / 128), 256, 0, stream>>>(
        attnb, out_w + (size_t)l * C_ * C_, x, x, skip_a + l, res_a + l,
        BT_, C_, C_);
    ln_kernel<<<BT_, 256, 0, stream>>>(x, ln2_w + l * C_, ln2_b + l * C_, hbuf);
    gemm_mfma<1><<<dim3(FF_ / 128, BT_ / 128), 256, 0, stream>>>(
        hbuf, fc1_w + (size_t)l * FF_ * C_, ffb, nullptr, nullptr, nullptr,
        BT_, FF_, C_);
    gemm_mfma<2><<<dim3(C_ / 128, BT_ / 128), 256, 0, stream>>>(
        ffb, fc2_w + (size_t)l * C_ * FF_, x, x, skip_m + l, res_m + l,
        BT_, C_, FF_);
  }

  ln_kernel<<<BT_, 256, 0, stream>>>(x, lnf_w, lnf_b, hbuf);
  gemm_mfma<0><<<dim3((VP_ + 127) / 128, BT_ / 128), 256, 0, stream>>>(
      hbuf, pos_head, out, nullptr, nullptr, nullptr, BT_, VP_, C_);
  gemm_mfma<0><<<dim3(VF_ / 128, BT_ / 128), 256, 0, stream>>>(
      hbuf, feat_head, out + (size_t)BT_ * VP_, nullptr, nullptr, nullptr,
      BT_, VF_, C_);
}